// Round 1
// baseline (2279.782 us; speedup 1.0000x reference)
//
#include <hip/hip_runtime.h>

typedef unsigned short u16;
typedef __attribute__((ext_vector_type(8))) __bf16 bf16x8;
typedef __attribute__((ext_vector_type(4))) float floatx4;

#define NUM_LAYERS 4
#define STEPS 8
#define LRS 0.1f
#define M_ROWS 4096            // B*S
#define D_DIM 1024
#define V_DIM 32000
#define SM ((size_t)M_ROWS * D_DIM)      // 4194304 elements per state buffer
#define WM ((size_t)D_DIM * D_DIM)       // 1048576 elements per W

__device__ __forceinline__ u16 f2b(float f) {
    union { float f; unsigned u; } c; c.f = f;
    unsigned u = c.u;
    u = (u + 0x7FFFu + ((u >> 16) & 1u)) >> 16;   // RNE
    return (u16)u;
}
__device__ __forceinline__ float b2f(u16 b) {
    union { unsigned u; float f; } c; c.u = ((unsigned)b) << 16;
    return c.f;
}

// ---------------------------------------------------------------------------
// Shared GEMM core: C(128x128 f32 acc) = A(M x K bf16, row-major, lda=K)
//                                      @ B^T(N x K bf16, row-major, ldb=K)
// 256 threads = 4 waves in 2x2; each wave 64x64 = 4x4 frags of 16x16x32 MFMA.
// LDS tiles 128 x 32, padded row stride 40 elems (80B -> 2-way conflicts only).
// ---------------------------------------------------------------------------
__device__ __forceinline__ void gemm_core(const u16* __restrict__ A,
                                          const u16* __restrict__ B,
                                          int m0, int n0, int K,
                                          floatx4 (&acc)[4][4]) {
    __shared__ u16 a_lds[128 * 40];
    __shared__ u16 b_lds[128 * 40];
    const int tid  = threadIdx.x;
    const int lane = tid & 63;
    const int wave = tid >> 6;
    const int wm = wave >> 1, wn = wave & 1;
    const int q = lane >> 4, lr = lane & 15;
    const int srow = tid >> 2;          // 0..63
    const int scol = (tid & 3) * 8;     // 0,8,16,24

    #pragma unroll
    for (int i = 0; i < 4; i++)
        #pragma unroll
        for (int j = 0; j < 4; j++)
            acc[i][j] = floatx4{0.f, 0.f, 0.f, 0.f};

    for (int kt = 0; kt < K; kt += 32) {
        uint4 a0 = *(const uint4*)(A + (size_t)(m0 + srow)      * K + kt + scol);
        uint4 a1 = *(const uint4*)(A + (size_t)(m0 + srow + 64) * K + kt + scol);
        uint4 b0 = *(const uint4*)(B + (size_t)(n0 + srow)      * K + kt + scol);
        uint4 b1 = *(const uint4*)(B + (size_t)(n0 + srow + 64) * K + kt + scol);
        __syncthreads();
        *(uint4*)&a_lds[srow * 40 + scol]        = a0;
        *(uint4*)&a_lds[(srow + 64) * 40 + scol] = a1;
        *(uint4*)&b_lds[srow * 40 + scol]        = b0;
        *(uint4*)&b_lds[(srow + 64) * 40 + scol] = b1;
        __syncthreads();
        bf16x8 af[4], bfv[4];
        #pragma unroll
        for (int mi = 0; mi < 4; mi++)
            af[mi] = *(const bf16x8*)&a_lds[(wm * 64 + mi * 16 + lr) * 40 + q * 8];
        #pragma unroll
        for (int ni = 0; ni < 4; ni++)
            bfv[ni] = *(const bf16x8*)&b_lds[(wn * 64 + ni * 16 + lr) * 40 + q * 8];
        #pragma unroll
        for (int mi = 0; mi < 4; mi++)
            #pragma unroll
            for (int ni = 0; ni < 4; ni++)
                acc[mi][ni] = __builtin_amdgcn_mfma_f32_16x16x32_bf16(
                    af[mi], bfv[ni], acc[mi][ni], 0, 0, 0);
    }
}

// eps_l = lower - b - mu_l @ W^T   (written as bf16); z = l-1 in 0..3
__global__ __launch_bounds__(256) void eps_gemm_k(
        const u16* __restrict__ sbf, const u16* __restrict__ Wbf,
        const float* __restrict__ x32, const float* __restrict__ s32,
        const float* __restrict__ b_stack, u16* __restrict__ epsb) {
    const int z = blockIdx.z;
    const int m0 = blockIdx.y * 128, n0 = blockIdx.x * 128;
    floatx4 acc[4][4];
    gemm_core(sbf + (size_t)z * SM, Wbf + (size_t)z * WM, m0, n0, D_DIM, acc);
    const float* lower = (z == 0) ? x32 : (s32 + (size_t)(z - 1) * SM);
    const float* bias  = b_stack + z * D_DIM;
    u16* eo = epsb + (size_t)z * SM;
    const int tid = threadIdx.x, lane = tid & 63, wave = tid >> 6;
    const int wm = wave >> 1, wn = wave & 1, q = lane >> 4, lr = lane & 15;
    #pragma unroll
    for (int mi = 0; mi < 4; mi++)
        #pragma unroll
        for (int ni = 0; ni < 4; ni++) {
            const int gcol = n0 + wn * 64 + ni * 16 + lr;
            const float bc = bias[gcol];
            #pragma unroll
            for (int r = 0; r < 4; r++) {
                const int grow = m0 + wm * 64 + mi * 16 + q * 4 + r;
                const size_t idx = (size_t)grow * D_DIM + gcol;
                eo[idx] = f2b(lower[idx] - bc - acc[mi][ni][r]);
            }
        }
}

// s_l += LR*(eps_l @ W) - LR*eps_{l+1};  W given as WT (row-major j,k=i)
__global__ __launch_bounds__(256) void upd_gemm_k(
        const u16* __restrict__ epsb, const u16* __restrict__ WTbf,
        float* __restrict__ s32, u16* __restrict__ sbf) {
    const int z = blockIdx.z;
    const int m0 = blockIdx.y * 128, n0 = blockIdx.x * 128;
    floatx4 acc[4][4];
    gemm_core(epsb + (size_t)z * SM, WTbf + (size_t)z * WM, m0, n0, D_DIM, acc);
    float* S  = s32 + (size_t)z * SM;
    u16*  Sb  = sbf + (size_t)z * SM;
    const bool hn = (z < 3);
    const u16* en = epsb + (size_t)(hn ? (z + 1) : z) * SM;
    const int tid = threadIdx.x, lane = tid & 63, wave = tid >> 6;
    const int wm = wave >> 1, wn = wave & 1, q = lane >> 4, lr = lane & 15;
    #pragma unroll
    for (int mi = 0; mi < 4; mi++)
        #pragma unroll
        for (int ni = 0; ni < 4; ni++) {
            const int gcol = n0 + wn * 64 + ni * 16 + lr;
            #pragma unroll
            for (int r = 0; r < 4; r++) {
                const int grow = m0 + wm * 64 + mi * 16 + q * 4 + r;
                const size_t idx = (size_t)grow * D_DIM + gcol;
                float v = S[idx] + LRS * acc[mi][ni][r];
                if (hn) v -= LRS * b2f(en[idx]);
                S[idx] = v;
                Sb[idx] = f2b(v);
            }
        }
}

// logits tile + fused online-softmax partials + target-logit capture
__global__ __launch_bounds__(256) void logits_k(
        const u16* __restrict__ s4bf, const u16* __restrict__ oWb,
        const float* __restrict__ out_b, const int* __restrict__ targets,
        float* __restrict__ part_m, float* __restrict__ part_s,
        float* __restrict__ tlog) {
    const int m0 = blockIdx.y * 128, n0 = blockIdx.x * 128;
    floatx4 acc[4][4];
    gemm_core(s4bf, oWb, m0, n0, D_DIM, acc);
    __shared__ float redm[128][2];
    __shared__ float reds[128][2];
    const int tid = threadIdx.x, lane = tid & 63, wave = tid >> 6;
    const int wm = wave >> 1, wn = wave & 1, q = lane >> 4, lr = lane & 15;
    float ob[4];
    #pragma unroll
    for (int ni = 0; ni < 4; ni++) ob[ni] = out_b[n0 + wn * 64 + ni * 16 + lr];
    #pragma unroll
    for (int mi = 0; mi < 4; mi++) {
        #pragma unroll
        for (int r = 0; r < 4; r++) {
            const int grow = m0 + wm * 64 + mi * 16 + q * 4 + r;
            float l[4];
            #pragma unroll
            for (int ni = 0; ni < 4; ni++) l[ni] = acc[mi][ni][r] + ob[ni];
            if ((grow & 511) != 511) {           // valid row (s < 511)
                const int t = targets[grow + 1];
                #pragma unroll
                for (int ni = 0; ni < 4; ni++) {
                    const int gcol = n0 + wn * 64 + ni * 16 + lr;
                    if (t == gcol) tlog[grow] = l[ni];
                }
            }
            float mx = fmaxf(fmaxf(l[0], l[1]), fmaxf(l[2], l[3]));
            #pragma unroll
            for (int off = 1; off < 16; off <<= 1)
                mx = fmaxf(mx, __shfl_xor(mx, off, 64));
            float sm = expf(l[0] - mx) + expf(l[1] - mx) +
                       expf(l[2] - mx) + expf(l[3] - mx);
            #pragma unroll
            for (int off = 1; off < 16; off <<= 1)
                sm += __shfl_xor(sm, off, 64);
            if (lr == 0) {
                const int rrow = wm * 64 + mi * 16 + q * 4 + r;
                redm[rrow][wn] = mx;
                reds[rrow][wn] = sm;
            }
        }
    }
    __syncthreads();
    if (tid < 128) {
        float ma = redm[tid][0], mb = redm[tid][1];
        float M = fmaxf(ma, mb);
        float S = reds[tid][0] * expf(ma - M) + reds[tid][1] * expf(mb - M);
        part_m[(size_t)blockIdx.x * M_ROWS + m0 + tid] = M;
        part_s[(size_t)blockIdx.x * M_ROWS + m0 + tid] = S;
    }
}

__global__ void gather_k(const int* __restrict__ ids,
                         const float* __restrict__ emb,
                         float* __restrict__ x32) {
    const int row = blockIdx.x;
    const int c = threadIdx.x * 4;
    float4 v = *(const float4*)(emb + (size_t)ids[row] * D_DIM + c);
    *(float4*)(x32 + (size_t)row * D_DIM + c) = v;
}

__global__ void conv_w_k(const float* __restrict__ W,
                         u16* __restrict__ Wbf, u16* __restrict__ WTbf) {
    __shared__ float t[32][33];
    const int z = blockIdx.z;
    const int i = blockIdx.y * 32 + threadIdx.y;
    const int j = blockIdx.x * 32 + threadIdx.x;
    const float v = W[(size_t)z * WM + (size_t)i * D_DIM + j];
    Wbf[(size_t)z * WM + (size_t)i * D_DIM + j] = f2b(v);
    t[threadIdx.y][threadIdx.x] = v;
    __syncthreads();
    const int jo = blockIdx.x * 32 + threadIdx.y;
    const int io = blockIdx.y * 32 + threadIdx.x;
    WTbf[(size_t)z * WM + (size_t)jo * D_DIM + io] = f2b(t[threadIdx.x][threadIdx.y]);
}

__device__ __forceinline__ unsigned pk2(float a, float b) {
    return (unsigned)f2b(a) | ((unsigned)f2b(b) << 16);
}

__global__ void conv_outw_k(const float* __restrict__ oW, u16* __restrict__ oWb) {
    const size_t i = ((size_t)blockIdx.x * 256 + threadIdx.x) * 4;
    float4 v = *(const float4*)(oW + i);
    uint2 o; o.x = pk2(v.x, v.y); o.y = pk2(v.z, v.w);
    *(uint2*)(oWb + i) = o;
}

__global__ void init_states_k(const float* __restrict__ si,
                              float* __restrict__ s32, u16* __restrict__ sbf) {
    const size_t i = ((size_t)blockIdx.x * 256 + threadIdx.x) * 4;
    float4 v = *(const float4*)(si + i);
    *(float4*)(s32 + i) = v;
    uint2 o; o.x = pk2(v.x, v.y); o.y = pk2(v.z, v.w);
    *(uint2*)(sbf + i) = o;
}

__device__ __forceinline__ float sq2(unsigned w) {
    float a = b2f((u16)(w & 0xffffu));
    float b = b2f((u16)(w >> 16));
    return a * a + b * b;
}

__global__ void pc_reduce_k(const u16* __restrict__ epsb, float* __restrict__ pc_sum) {
    const size_t n8 = (4 * SM) / 8;
    const size_t stride = (size_t)gridDim.x * blockDim.x;
    float s = 0.f;
    for (size_t i = (size_t)blockIdx.x * blockDim.x + threadIdx.x; i < n8; i += stride) {
        uint4 u = *(const uint4*)(epsb + i * 8);
        s += sq2(u.x) + sq2(u.y) + sq2(u.z) + sq2(u.w);
    }
    #pragma unroll
    for (int off = 1; off < 64; off <<= 1) s += __shfl_xor(s, off, 64);
    __shared__ float ls[4];
    if ((threadIdx.x & 63) == 0) ls[threadIdx.x >> 6] = s;
    __syncthreads();
    if (threadIdx.x == 0) atomicAdd(pc_sum, ls[0] + ls[1] + ls[2] + ls[3]);
}

__global__ void ce_reduce_k(const float* __restrict__ part_m,
                            const float* __restrict__ part_s,
                            const float* __restrict__ tlog,
                            float* __restrict__ ce_sum) {
    const int row = blockIdx.x;
    if ((row & 511) == 511) return;
    const int tid = threadIdx.x;
    const int NT = V_DIM / 128;  // 250
    float m = -3.0e38f;
    for (int nt = tid; nt < NT; nt += 256)
        m = fmaxf(m, part_m[(size_t)nt * M_ROWS + row]);
    #pragma unroll
    for (int off = 1; off < 64; off <<= 1) m = fmaxf(m, __shfl_xor(m, off, 64));
    __shared__ float sm[4], ss[4];
    if ((tid & 63) == 0) sm[tid >> 6] = m;
    __syncthreads();
    m = fmaxf(fmaxf(sm[0], sm[1]), fmaxf(sm[2], sm[3]));
    float s = 0.f;
    for (int nt = tid; nt < NT; nt += 256)
        s += part_s[(size_t)nt * M_ROWS + row] *
             expf(part_m[(size_t)nt * M_ROWS + row] - m);
    #pragma unroll
    for (int off = 1; off < 64; off <<= 1) s += __shfl_xor(s, off, 64);
    if ((tid & 63) == 0) ss[tid >> 6] = s;
    __syncthreads();
    if (tid == 0) {
        float loss = m + logf(ss[0] + ss[1] + ss[2] + ss[3]) - tlog[row];
        atomicAdd(ce_sum, loss);
    }
}

__global__ void finalize_k(const float* __restrict__ scal, float* __restrict__ out) {
    out[0] = scal[0] / 4088.0f;
    out[1] = scal[1] / (float)(4 * SM);
}

extern "C" void kernel_launch(void* const* d_in, const int* in_sizes, int n_in,
                              void* d_out, int out_size, void* d_ws, size_t ws_size,
                              hipStream_t stream) {
    (void)in_sizes; (void)n_in; (void)out_size; (void)ws_size;
    const int*   ids = (const int*)d_in[0];
    const int*   tgt = (const int*)d_in[1];
    const float* emb = (const float*)d_in[2];
    const float* W   = (const float*)d_in[3];
    const float* bs  = (const float*)d_in[4];
    const float* oW  = (const float*)d_in[5];
    const float* ob  = (const float*)d_in[6];
    const float* si  = (const float*)d_in[7];

    char* ws = (char*)d_ws;
    float* s32    = (float*)(ws + 0);             // 67,108,864 B
    float* x32    = (float*)(ws + 67108864);      // 16,777,216 B
    u16*   sbf    = (u16*)  (ws + 83886080);      // 33,554,432 B
    u16*   epsb   = (u16*)  (ws + 117440512);     // 33,554,432 B
    u16*   Wbf    = (u16*)  (ws + 150994944);     //  8,388,608 B
    u16*   WTbf   = (u16*)  (ws + 159383552);     //  8,388,608 B
    u16*   oWb    = (u16*)  (ws + 167772160);     // 65,536,000 B
    float* part_m = (float*)(ws + 233308160);     //  4,096,000 B
    float* part_s = (float*)(ws + 237404160);     //  4,096,000 B
    float* tlog   = (float*)(ws + 241500160);     //     16,384 B
    float* scal   = (float*)(ws + 241516544);     //        256 B

    hipMemsetAsync(scal, 0, 256, stream);
    gather_k<<<M_ROWS, 256, 0, stream>>>(ids, emb, x32);
    conv_w_k<<<dim3(32, 32, 4), dim3(32, 32), 0, stream>>>(W, Wbf, WTbf);
    conv_outw_k<<<(V_DIM * D_DIM) / 1024, 256, 0, stream>>>(oW, oWb);
    init_states_k<<<(4 * (int)SM) / 1024, 256, 0, stream>>>(si, s32, sbf);

    for (int step = 0; step < STEPS; ++step) {
        eps_gemm_k<<<dim3(8, 32, 4), 256, 0, stream>>>(sbf, Wbf, x32, s32, bs, epsb);
        upd_gemm_k<<<dim3(8, 32, 4), 256, 0, stream>>>(epsb, WTbf, s32, sbf);
    }
    eps_gemm_k<<<dim3(8, 32, 4), 256, 0, stream>>>(sbf, Wbf, x32, s32, bs, epsb);
    pc_reduce_k<<<1024, 256, 0, stream>>>(epsb, scal + 1);
    logits_k<<<dim3(V_DIM / 128, 32), 256, 0, stream>>>(sbf + 3 * SM, oWb, ob, tgt,
                                                        part_m, part_s, tlog);
    ce_reduce_k<<<M_ROWS, 256, 0, stream>>>(part_m, part_s, tlog, scal);
    finalize_k<<<1, 1, 0, stream>>>(scal, (float*)d_out);
}

// Round 2
// 2228.450 us; speedup vs baseline: 1.0230x; 1.0230x over previous
//
#include <hip/hip_runtime.h>

typedef unsigned short u16;
typedef __attribute__((ext_vector_type(8))) __bf16 bf16x8;
typedef __attribute__((ext_vector_type(4))) float floatx4;

#define NUM_LAYERS 4
#define STEPS 8
#define LRS 0.1f
#define M_ROWS 4096            // B*S
#define D_DIM 1024
#define V_DIM 32000
#define SM ((size_t)M_ROWS * D_DIM)      // 4194304 elements per state buffer
#define WM ((size_t)D_DIM * D_DIM)       // 1048576 elements per W

__device__ __forceinline__ u16 f2b(float f) {
    union { float f; unsigned u; } c; c.f = f;
    unsigned u = c.u;
    u = (u + 0x7FFFu + ((u >> 16) & 1u)) >> 16;   // RNE
    return (u16)u;
}
__device__ __forceinline__ float b2f(u16 b) {
    union { unsigned u; float f; } c; c.u = ((unsigned)b) << 16;
    return c.f;
}

// async 16B global -> LDS (wave-uniform LDS base + lane*16)
__device__ __forceinline__ void ld16(const u16* g, u16* l) {
    __builtin_amdgcn_global_load_lds(
        (const __attribute__((address_space(1))) void*)g,
        (__attribute__((address_space(3))) void*)l, 16, 0, 0);
}

// ---------------------------------------------------------------------------
// Shared GEMM core: C(128x128 f32 acc) = A(M x K bf16, row-major, lda=K)
//                                      @ B^T(N x K bf16, row-major, ldb=K)
// 256 threads = 4 waves in 2x2; each wave 64x64 = 4x4 frags of 16x16x32 MFMA.
// m97 structure: global_load_lds width=16 staging, UNPADDED stride-32 LDS
// (64 B/row -> wave's ds_read_b128 set covers 1024 contiguous B: conflict-free,
// and global_load_lds requires the contiguous lane-order layout).
// ---------------------------------------------------------------------------
__device__ __forceinline__ void gemm_core(const u16* __restrict__ A,
                                          const u16* __restrict__ B,
                                          int m0, int n0, int K,
                                          floatx4 (&acc)[4][4]) {
    __shared__ __align__(16) u16 a_lds[128 * 32];
    __shared__ __align__(16) u16 b_lds[128 * 32];
    const int tid  = threadIdx.x;
    const int lane = tid & 63;
    const int wave = tid >> 6;
    const int wm = wave >> 1, wn = wave & 1;
    const int q = lane >> 4, lr = lane & 15;

    // staging map: chunk c = j*256 + wave*64 + lane covers LDS bytes [c*16, c*16+16)
    // -> row = c/4 = j*64 + wave*16 + (lane>>2), colchunk = (lane&3)*8 u16
    const int r0 = wave * 16 + (lane >> 2);
    const int cc = (lane & 3) * 8;
    const u16* ga0 = A + (size_t)(m0 + r0)      * K + cc;
    const u16* ga1 = A + (size_t)(m0 + r0 + 64) * K + cc;
    const u16* gb0 = B + (size_t)(n0 + r0)      * K + cc;
    const u16* gb1 = B + (size_t)(n0 + r0 + 64) * K + cc;
    u16* la0 = &a_lds[wave * 512];
    u16* la1 = &a_lds[2048 + wave * 512];
    u16* lb0 = &b_lds[wave * 512];
    u16* lb1 = &b_lds[2048 + wave * 512];

    #pragma unroll
    for (int i = 0; i < 4; i++)
        #pragma unroll
        for (int j = 0; j < 4; j++)
            acc[i][j] = floatx4{0.f, 0.f, 0.f, 0.f};

    for (int kt = 0; kt < K; kt += 32) {
        __syncthreads();                 // previous iter's LDS reads done
        ld16(ga0 + kt, la0);
        ld16(ga1 + kt, la1);
        ld16(gb0 + kt, lb0);
        ld16(gb1 + kt, lb1);
        __syncthreads();                 // drains vmcnt before reads
        bf16x8 af[4], bfv[4];
        #pragma unroll
        for (int mi = 0; mi < 4; mi++)
            af[mi] = *(const bf16x8*)&a_lds[(wm * 64 + mi * 16 + lr) * 32 + q * 8];
        #pragma unroll
        for (int ni = 0; ni < 4; ni++)
            bfv[ni] = *(const bf16x8*)&b_lds[(wn * 64 + ni * 16 + lr) * 32 + q * 8];
        #pragma unroll
        for (int mi = 0; mi < 4; mi++)
            #pragma unroll
            for (int ni = 0; ni < 4; ni++)
                acc[mi][ni] = __builtin_amdgcn_mfma_f32_16x16x32_bf16(
                    af[mi], bfv[ni], acc[mi][ni], 0, 0, 0);
    }
}

// eps_l = lower - b - mu_l @ W^T   (written as bf16); z = l-1 in 0..3
__global__ __launch_bounds__(256) void eps_gemm_k(
        const u16* __restrict__ sbf, const u16* __restrict__ Wbf,
        const float* __restrict__ x32, const float* __restrict__ s32,
        const float* __restrict__ b_stack, u16* __restrict__ epsb) {
    const int z = blockIdx.z;
    const int m0 = blockIdx.y * 128, n0 = blockIdx.x * 128;
    floatx4 acc[4][4];
    gemm_core(sbf + (size_t)z * SM, Wbf + (size_t)z * WM, m0, n0, D_DIM, acc);
    const float* lower = (z == 0) ? x32 : (s32 + (size_t)(z - 1) * SM);
    const float* bias  = b_stack + z * D_DIM;
    u16* eo = epsb + (size_t)z * SM;
    const int tid = threadIdx.x, lane = tid & 63, wave = tid >> 6;
    const int wm = wave >> 1, wn = wave & 1, q = lane >> 4, lr = lane & 15;
    #pragma unroll
    for (int mi = 0; mi < 4; mi++)
        #pragma unroll
        for (int ni = 0; ni < 4; ni++) {
            const int gcol = n0 + wn * 64 + ni * 16 + lr;
            const float bc = bias[gcol];
            #pragma unroll
            for (int r = 0; r < 4; r++) {
                const int grow = m0 + wm * 64 + mi * 16 + q * 4 + r;
                const size_t idx = (size_t)grow * D_DIM + gcol;
                eo[idx] = f2b(lower[idx] - bc - acc[mi][ni][r]);
            }
        }
}

// s_l += LR*(eps_l @ W) - LR*eps_{l+1};  W given as WT (row-major j,k=i)
__global__ __launch_bounds__(256) void upd_gemm_k(
        const u16* __restrict__ epsb, const u16* __restrict__ WTbf,
        float* __restrict__ s32, u16* __restrict__ sbf) {
    const int z = blockIdx.z;
    const int m0 = blockIdx.y * 128, n0 = blockIdx.x * 128;
    floatx4 acc[4][4];
    gemm_core(epsb + (size_t)z * SM, WTbf + (size_t)z * WM, m0, n0, D_DIM, acc);
    float* S  = s32 + (size_t)z * SM;
    u16*  Sb  = sbf + (size_t)z * SM;
    const bool hn = (z < 3);
    const u16* en = epsb + (size_t)(hn ? (z + 1) : z) * SM;
    const int tid = threadIdx.x, lane = tid & 63, wave = tid >> 6;
    const int wm = wave >> 1, wn = wave & 1, q = lane >> 4, lr = lane & 15;
    #pragma unroll
    for (int mi = 0; mi < 4; mi++)
        #pragma unroll
        for (int ni = 0; ni < 4; ni++) {
            const int gcol = n0 + wn * 64 + ni * 16 + lr;
            #pragma unroll
            for (int r = 0; r < 4; r++) {
                const int grow = m0 + wm * 64 + mi * 16 + q * 4 + r;
                const size_t idx = (size_t)grow * D_DIM + gcol;
                float v = S[idx] + LRS * acc[mi][ni][r];
                if (hn) v -= LRS * b2f(en[idx]);
                S[idx] = v;
                Sb[idx] = f2b(v);
            }
        }
}

// logits tile + fused online-softmax partials + target-logit capture
// grid: x = m-tile (32, fastest) so co-resident blocks share one B n-strip -> L2
__global__ __launch_bounds__(256) void logits_k(
        const u16* __restrict__ s4bf, const u16* __restrict__ oWb,
        const float* __restrict__ out_b, const int* __restrict__ targets,
        float* __restrict__ part_m, float* __restrict__ part_s,
        float* __restrict__ tlog) {
    const int m0 = blockIdx.x * 128, n0 = blockIdx.y * 128;
    floatx4 acc[4][4];
    gemm_core(s4bf, oWb, m0, n0, D_DIM, acc);
    __shared__ float redm[128][2];
    __shared__ float reds[128][2];
    const int tid = threadIdx.x, lane = tid & 63, wave = tid >> 6;
    const int wm = wave >> 1, wn = wave & 1, q = lane >> 4, lr = lane & 15;
    float ob[4];
    #pragma unroll
    for (int ni = 0; ni < 4; ni++) ob[ni] = out_b[n0 + wn * 64 + ni * 16 + lr];
    #pragma unroll
    for (int mi = 0; mi < 4; mi++) {
        #pragma unroll
        for (int r = 0; r < 4; r++) {
            const int grow = m0 + wm * 64 + mi * 16 + q * 4 + r;
            float l[4];
            #pragma unroll
            for (int ni = 0; ni < 4; ni++) l[ni] = acc[mi][ni][r] + ob[ni];
            if ((grow & 511) != 511) {           // valid row (s < 511)
                const int t = targets[grow + 1];
                #pragma unroll
                for (int ni = 0; ni < 4; ni++) {
                    const int gcol = n0 + wn * 64 + ni * 16 + lr;
                    if (t == gcol) tlog[grow] = l[ni];
                }
            }
            float mx = fmaxf(fmaxf(l[0], l[1]), fmaxf(l[2], l[3]));
            #pragma unroll
            for (int off = 1; off < 16; off <<= 1)
                mx = fmaxf(mx, __shfl_xor(mx, off, 64));
            float sm = expf(l[0] - mx) + expf(l[1] - mx) +
                       expf(l[2] - mx) + expf(l[3] - mx);
            #pragma unroll
            for (int off = 1; off < 16; off <<= 1)
                sm += __shfl_xor(sm, off, 64);
            if (lr == 0) {
                const int rrow = wm * 64 + mi * 16 + q * 4 + r;
                redm[rrow][wn] = mx;
                reds[rrow][wn] = sm;
            }
        }
    }
    __syncthreads();
    if (tid < 128) {
        float ma = redm[tid][0], mb = redm[tid][1];
        float M = fmaxf(ma, mb);
        float S = reds[tid][0] * expf(ma - M) + reds[tid][1] * expf(mb - M);
        part_m[(size_t)blockIdx.y * M_ROWS + m0 + tid] = M;
        part_s[(size_t)blockIdx.y * M_ROWS + m0 + tid] = S;
    }
}

__global__ void gather_k(const int* __restrict__ ids,
                         const float* __restrict__ emb,
                         float* __restrict__ x32) {
    const int row = blockIdx.x;
    const int c = threadIdx.x * 4;
    float4 v = *(const float4*)(emb + (size_t)ids[row] * D_DIM + c);
    *(float4*)(x32 + (size_t)row * D_DIM + c) = v;
}

__global__ void conv_w_k(const float* __restrict__ W,
                         u16* __restrict__ Wbf, u16* __restrict__ WTbf) {
    __shared__ float t[32][33];
    const int z = blockIdx.z;
    const int i = blockIdx.y * 32 + threadIdx.y;
    const int j = blockIdx.x * 32 + threadIdx.x;
    const float v = W[(size_t)z * WM + (size_t)i * D_DIM + j];
    Wbf[(size_t)z * WM + (size_t)i * D_DIM + j] = f2b(v);
    t[threadIdx.y][threadIdx.x] = v;
    __syncthreads();
    const int jo = blockIdx.x * 32 + threadIdx.y;
    const int io = blockIdx.y * 32 + threadIdx.x;
    WTbf[(size_t)z * WM + (size_t)jo * D_DIM + io] = f2b(t[threadIdx.x][threadIdx.y]);
}

__device__ __forceinline__ unsigned pk2(float a, float b) {
    return (unsigned)f2b(a) | ((unsigned)f2b(b) << 16);
}

__global__ void conv_outw_k(const float* __restrict__ oW, u16* __restrict__ oWb) {
    const size_t i = ((size_t)blockIdx.x * 256 + threadIdx.x) * 4;
    float4 v = *(const float4*)(oW + i);
    uint2 o; o.x = pk2(v.x, v.y); o.y = pk2(v.z, v.w);
    *(uint2*)(oWb + i) = o;
}

__global__ void init_states_k(const float* __restrict__ si,
                              float* __restrict__ s32, u16* __restrict__ sbf) {
    const size_t i = ((size_t)blockIdx.x * 256 + threadIdx.x) * 4;
    float4 v = *(const float4*)(si + i);
    *(float4*)(s32 + i) = v;
    uint2 o; o.x = pk2(v.x, v.y); o.y = pk2(v.z, v.w);
    *(uint2*)(sbf + i) = o;
}

__device__ __forceinline__ float sq2(unsigned w) {
    float a = b2f((u16)(w & 0xffffu));
    float b = b2f((u16)(w >> 16));
    return a * a + b * b;
}

__global__ void pc_reduce_k(const u16* __restrict__ epsb, float* __restrict__ pc_sum) {
    const size_t n8 = (4 * SM) / 8;
    const size_t stride = (size_t)gridDim.x * blockDim.x;
    float s = 0.f;
    for (size_t i = (size_t)blockIdx.x * blockDim.x + threadIdx.x; i < n8; i += stride) {
        uint4 u = *(const uint4*)(epsb + i * 8);
        s += sq2(u.x) + sq2(u.y) + sq2(u.z) + sq2(u.w);
    }
    #pragma unroll
    for (int off = 1; off < 64; off <<= 1) s += __shfl_xor(s, off, 64);
    __shared__ float ls[4];
    if ((threadIdx.x & 63) == 0) ls[threadIdx.x >> 6] = s;
    __syncthreads();
    if (threadIdx.x == 0) atomicAdd(pc_sum, ls[0] + ls[1] + ls[2] + ls[3]);
}

__global__ void ce_reduce_k(const float* __restrict__ part_m,
                            const float* __restrict__ part_s,
                            const float* __restrict__ tlog,
                            float* __restrict__ ce_sum) {
    const int row = blockIdx.x;
    if ((row & 511) == 511) return;
    const int tid = threadIdx.x;
    const int NT = V_DIM / 128;  // 250
    float m = -3.0e38f;
    for (int nt = tid; nt < NT; nt += 256)
        m = fmaxf(m, part_m[(size_t)nt * M_ROWS + row]);
    #pragma unroll
    for (int off = 1; off < 64; off <<= 1) m = fmaxf(m, __shfl_xor(m, off, 64));
    __shared__ float sm[4], ss[4];
    if ((tid & 63) == 0) sm[tid >> 6] = m;
    __syncthreads();
    m = fmaxf(fmaxf(sm[0], sm[1]), fmaxf(sm[2], sm[3]));
    float s = 0.f;
    for (int nt = tid; nt < NT; nt += 256)
        s += part_s[(size_t)nt * M_ROWS + row] *
             expf(part_m[(size_t)nt * M_ROWS + row] - m);
    #pragma unroll
    for (int off = 1; off < 64; off <<= 1) s += __shfl_xor(s, off, 64);
    if ((tid & 63) == 0) ss[tid >> 6] = s;
    __syncthreads();
    if (tid == 0) {
        float loss = m + logf(ss[0] + ss[1] + ss[2] + ss[3]) - tlog[row];
        atomicAdd(ce_sum, loss);
    }
}

__global__ void finalize_k(const float* __restrict__ scal, float* __restrict__ out) {
    out[0] = scal[0] / 4088.0f;
    out[1] = scal[1] / (float)(4 * SM);
}

extern "C" void kernel_launch(void* const* d_in, const int* in_sizes, int n_in,
                              void* d_out, int out_size, void* d_ws, size_t ws_size,
                              hipStream_t stream) {
    (void)in_sizes; (void)n_in; (void)out_size; (void)ws_size;
    const int*   ids = (const int*)d_in[0];
    const int*   tgt = (const int*)d_in[1];
    const float* emb = (const float*)d_in[2];
    const float* W   = (const float*)d_in[3];
    const float* bs  = (const float*)d_in[4];
    const float* oW  = (const float*)d_in[5];
    const float* ob  = (const float*)d_in[6];
    const float* si  = (const float*)d_in[7];

    char* ws = (char*)d_ws;
    float* s32    = (float*)(ws + 0);             // 67,108,864 B
    float* x32    = (float*)(ws + 67108864);      // 16,777,216 B
    u16*   sbf    = (u16*)  (ws + 83886080);      // 33,554,432 B
    u16*   epsb   = (u16*)  (ws + 117440512);     // 33,554,432 B
    u16*   Wbf    = (u16*)  (ws + 150994944);     //  8,388,608 B
    u16*   WTbf   = (u16*)  (ws + 159383552);     //  8,388,608 B
    u16*   oWb    = (u16*)  (ws + 167772160);     // 65,536,000 B
    float* part_m = (float*)(ws + 233308160);     //  4,096,000 B
    float* part_s = (float*)(ws + 237404160);     //  4,096,000 B
    float* tlog   = (float*)(ws + 241500160);     //     16,384 B
    float* scal   = (float*)(ws + 241516544);     //        256 B

    hipMemsetAsync(scal, 0, 256, stream);
    gather_k<<<M_ROWS, 256, 0, stream>>>(ids, emb, x32);
    conv_w_k<<<dim3(32, 32, 4), dim3(32, 32), 0, stream>>>(W, Wbf, WTbf);
    conv_outw_k<<<(V_DIM * D_DIM) / 1024, 256, 0, stream>>>(oW, oWb);
    init_states_k<<<(4 * (int)SM) / 1024, 256, 0, stream>>>(si, s32, sbf);

    for (int step = 0; step < STEPS; ++step) {
        eps_gemm_k<<<dim3(8, 32, 4), 256, 0, stream>>>(sbf, Wbf, x32, s32, bs, epsb);
        upd_gemm_k<<<dim3(8, 32, 4), 256, 0, stream>>>(epsb, WTbf, s32, sbf);
    }
    eps_gemm_k<<<dim3(8, 32, 4), 256, 0, stream>>>(sbf, Wbf, x32, s32, bs, epsb);
    pc_reduce_k<<<1024, 256, 0, stream>>>(epsb, scal + 1);
    logits_k<<<dim3(32, V_DIM / 128), 256, 0, stream>>>(sbf + 3 * SM, oWb, ob, tgt,
                                                        part_m, part_s, tlog);
    ce_reduce_k<<<M_ROWS, 256, 0, stream>>>(part_m, part_s, tlog, scal);
    finalize_k<<<1, 1, 0, stream>>>(scal, (float*)d_out);
}